// Round 7
// baseline (153.861 us; speedup 1.0000x reference)
//
#include <hip/hip_runtime.h>
#include <math.h>

#define BB   4
#define HH   96
#define WW   96
#define HW   (HH * WW)          // 9216
#define CIN  64
#define COUT 64
#define C2B  160                // bf16 concat channels padded 130 -> 160
#define NROW (BB * HW)          // 36864
#define ZROW NROW               // all-zero row for invalid conv taps
#define NSTRIP (NROW / 16)      // 2304 strips of 16 positions
#define NBLK (NSTRIP / 4)       // 576 blocks of 4 waves (4 strips)
#define BPX  (NBLK / 8)         // 72 blocks per XCD
#define NA   (9 * 32 * C2B)     // wa2 elements (46080)
#define NW   (9 * 64 * 64)      // wb2 elements (36864)
#define XBLK 145                // prep blocks covering NROW+1 rows
#define WBLK 324                // prep blocks covering NA+NW elements

typedef short v8s __attribute__((ext_vector_type(8)));   // 8 bf16 = 4 VGPRs
typedef float v4f __attribute__((ext_vector_type(4)));

__device__ __forceinline__ unsigned short f2bf(float f) {
    unsigned u = __float_as_uint(f);
    return (unsigned short)((u + 0x7FFFu + ((u >> 16) & 1u)) >> 16);  // RTN-even
}
__device__ __forceinline__ unsigned pack2(float a, float b) {
    return (unsigned)f2bf(a) | ((unsigned)f2bf(b) << 16);
}
// bilinear-combine one packed-bf16-pair dword from each of 4 corners
__device__ __forceinline__ unsigned bil2(unsigned a, unsigned b, unsigned c,
                                         unsigned d, float w00, float w01,
                                         float w10, float w11) {
    float lo = w00 * __uint_as_float(a << 16) + w01 * __uint_as_float(b << 16)
             + w10 * __uint_as_float(c << 16) + w11 * __uint_as_float(d << 16);
    float hi = w00 * __uint_as_float(a & 0xffff0000u)
             + w01 * __uint_as_float(b & 0xffff0000u)
             + w10 * __uint_as_float(c & 0xffff0000u)
             + w11 * __uint_as_float(d & 0xffff0000u);
    return pack2(lo, hi);
}

// ---------------------------------------------------------------------------
// Prep (single launch): blocks [0,XBLK) build Xt rows; blocks [XBLK,XBLK+WBLK)
// build Wa2/Wb2.
// Xt[row][160] bf16 = concat(fi[64], fj[64], flow[2], 0-pad); row ZROW = 0.
// Wa2[t][oc(32)][ch(160)]: oc 0..17 w_off, 18..26 w_mod, rest 0.
// Wb2[k][o(64)][ch(64)] = w_reg[o][c][k].
// ---------------------------------------------------------------------------
__global__ __launch_bounds__(256) void prep_kernel(
    const float* __restrict__ fi, const float* __restrict__ fj,
    const float* __restrict__ fl, const float* __restrict__ w_off,
    const float* __restrict__ w_mod, const float* __restrict__ w_reg,
    unsigned short* __restrict__ xt, unsigned short* __restrict__ wa2,
    unsigned short* __restrict__ wb2)
{
    int blk = blockIdx.x;
    if (blk < XBLK) {
        int r = blk * 256 + threadIdx.x;
        if (r > NROW) return;
        unsigned* dst = (unsigned*)(xt + (size_t)r * C2B);   // 80 dwords
        if (r == NROW) {
            for (int i = 0; i < 80; ++i) dst[i] = 0u;
            return;
        }
        int b = r / HW, hw = r % HW;
        const float* pi = fi + (size_t)b * CIN * HW + hw;
        const float* pj = fj + (size_t)b * CIN * HW + hw;
        const float* pf = fl + (size_t)b * 2 * HW + hw;
#pragma unroll 8
        for (int cp = 0; cp < 32; ++cp)
            dst[cp] = pack2(pi[(size_t)(2 * cp) * HW], pi[(size_t)(2 * cp + 1) * HW]);
#pragma unroll 8
        for (int cp = 0; cp < 32; ++cp)
            dst[32 + cp] = pack2(pj[(size_t)(2 * cp) * HW], pj[(size_t)(2 * cp + 1) * HW]);
        dst[64] = pack2(pf[0], pf[HW]);
#pragma unroll
        for (int i = 65; i < 80; ++i) dst[i] = 0u;
    } else {
        int e = (blk - XBLK) * 256 + threadIdx.x;
        if (e < NA) {
            int c  = e % C2B;
            int oc = (e / C2B) % 32;
            int t  = e / (C2B * 32);
            float v = 0.0f;
            if (oc < 27 && c < 130) {
                if (oc < 18) v = w_off[((size_t)oc * 130 + c) * 9 + t];
                else         v = w_mod[((size_t)(oc - 18) * 130 + c) * 9 + t];
            }
            wa2[e] = f2bf(v);
        } else {
            int e2 = e - NA;
            if (e2 < NW) {
                int c = e2 % 64;
                int o = (e2 / 64) % 64;
                int k = e2 / 4096;
                wb2[e2] = f2bf(w_reg[((size_t)o * 64 + c) * 9 + k]);
            }
        }
    }
}

// ---------------------------------------------------------------------------
// Fused conv (offset/mod) + deformable conv. Block = 4 waves = 4 strips of 16
// positions (L1 shares the identical weight streams across waves). Each wave:
//   Phase 1: implicit-GEMM conv, M=16 pos x N=32 oc, K=9x160. Epilogue applies
//     bias / 2*sigmoid and stores to per-wave LDS lraw[pos][28].
//   (one __syncthreads)
//   Phase 2: per tap, each lane (m,g) reads its own position's dy/dx/mod from
//     LDS, bilinear-gathers channels ks*32+g*8..+7 at 4 corners and combines
//     DIRECTLY into the MFMA A-fragment (no LDS round-trip, no per-tap
//     barrier -> taps pipeline freely). 8 MFMAs/tap, M=16 pos x N=64 out.
// ---------------------------------------------------------------------------
__global__ __launch_bounds__(256) void fused_kernel(
    const unsigned short* __restrict__ xt,
    const unsigned short* __restrict__ wa2,
    const unsigned short* __restrict__ wb2,
    const float* __restrict__ b_off, const float* __restrict__ b_mod,
    float* __restrict__ out)
{
    __shared__ float lraw[4][16 * 28];      // 7 KB, per-wave handoff

    int l = threadIdx.x & 63;
    int wid = __builtin_amdgcn_readfirstlane(threadIdx.x >> 6);
    int m = l & 15, g = l >> 4;
    int bstrip = (blockIdx.x & 7) * BPX + (blockIdx.x >> 3);  // 0..575
    int strip = bstrip * 4 + wid;           // 0..2303, wave-uniform
    int b = strip / (HW / 16);              // wave-uniform
    int hw0 = (strip - b * (HW / 16)) * 16;
    int hw = hw0 + m;
    int x = hw % WW, y = hw / WW;

    // ---- Phase 1: conv ----
    v4f acc0 = {0.f, 0.f, 0.f, 0.f};
    v4f acc1 = {0.f, 0.f, 0.f, 0.f};
#pragma unroll
    for (int t = 0; t < 9; ++t) {
        int ty = t / 3, tx = t - 3 * ty;
        int yy = y + ty - 1, xx = x + tx - 1;
        bool ok = ((unsigned)yy < HH) && ((unsigned)xx < WW);
        int row = ok ? (b * HW + yy * WW + xx) : ZROW;
        const unsigned short* ar = xt + (size_t)row * C2B + g * 8;
        const unsigned short* w0 = wa2 + ((size_t)(t * 32 + m)) * C2B + g * 8;
        const unsigned short* w1 = w0 + 16 * C2B;
#pragma unroll
        for (int ks = 0; ks < 5; ++ks) {
            v8s a  = *(const v8s*)(ar + ks * 32);
            v8s b0 = *(const v8s*)(w0 + ks * 32);
            v8s b1 = *(const v8s*)(w1 + ks * 32);
            acc0 = __builtin_amdgcn_mfma_f32_16x16x32_bf16(a, b0, acc0, 0, 0, 0);
            acc1 = __builtin_amdgcn_mfma_f32_16x16x32_bf16(a, b1, acc1, 0, 0, 0);
        }
    }

    // epilogue -> LDS: D row = g*4+reg (position), col = m (oc in n-tile)
    float* lr = lraw[wid];
    {
        float v0[4] = {acc0.x, acc0.y, acc0.z, acc0.w};
        float v1[4] = {acc1.x, acc1.y, acc1.z, acc1.w};
        float bo0 = b_off[m];
        int oc1 = 16 + m;
#pragma unroll
        for (int r = 0; r < 4; ++r)
            lr[(g * 4 + r) * 28 + m] = v0[r] + bo0;
        if (oc1 < 18) {
            float bo1 = b_off[oc1];
#pragma unroll
            for (int r = 0; r < 4; ++r)
                lr[(g * 4 + r) * 28 + oc1] = v1[r] + bo1;
        } else if (oc1 < 27) {
            float bm = b_mod[oc1 - 18];
#pragma unroll
            for (int r = 0; r < 4; ++r)
                lr[(g * 4 + r) * 28 + oc1] =
                    2.0f / (1.0f + expf(-(v1[r] + bm)));
        }
    }
    __syncthreads();

    // ---- Phase 2: deformable conv ----
    v4f acc[4];
#pragma unroll
    for (int nt = 0; nt < 4; ++nt) acc[nt] = (v4f){0.f, 0.f, 0.f, 0.f};

#pragma unroll
    for (int k = 0; k < 9; ++k) {
        int ky = k / 3, kx = k - 3 * ky;
        float dy = lr[m * 28 + 2 * k];
        float dx = lr[m * 28 + 2 * k + 1];
        float mm = lr[m * 28 + 18 + k];

        float py = (float)(y - 1 + ky) + dy;
        float px = (float)(x - 1 + kx) + dx;
        float fy = floorf(py), fx = floorf(px);
        int   y0 = (int)fy,    x0 = (int)fx;
        float wy = py - fy,    wx = px - fx;
        int   y1 = y0 + 1,     x1 = x0 + 1;

        bool y0v = (y0 >= 0) && (y0 < HH);
        bool y1v = (y1 >= 0) && (y1 < HH);
        bool x0v = (x0 >= 0) && (x0 < WW);
        bool x1v = (x1 >= 0) && (x1 < WW);

        float w00 = (1.f - wy) * (1.f - wx) * ((y0v && x0v) ? mm : 0.f);
        float w01 = (1.f - wy) * wx         * ((y0v && x1v) ? mm : 0.f);
        float w10 = wy * (1.f - wx)         * ((y1v && x0v) ? mm : 0.f);
        float w11 = wy * wx                 * ((y1v && x1v) ? mm : 0.f);

        int y0c = min(max(y0, 0), HH - 1), y1c = min(max(y1, 0), HH - 1);
        int x0c = min(max(x0, 0), WW - 1), x1c = min(max(x1, 0), WW - 1);
        int rb = b * HW;
        // fj channels at +64 in the row; lane's A-chunk = ks*32 + g*8
        const unsigned short* r00 = xt + (size_t)(rb + y0c * WW + x0c) * C2B + 64 + g * 8;
        const unsigned short* r01 = xt + (size_t)(rb + y0c * WW + x1c) * C2B + 64 + g * 8;
        const unsigned short* r10 = xt + (size_t)(rb + y1c * WW + x0c) * C2B + 64 + g * 8;
        const unsigned short* r11 = xt + (size_t)(rb + y1c * WW + x1c) * C2B + 64 + g * 8;

        v8s afrag[2];
#pragma unroll
        for (int ks = 0; ks < 2; ++ks) {
            uint4 u00 = *(const uint4*)(r00 + ks * 32);
            uint4 u01 = *(const uint4*)(r01 + ks * 32);
            uint4 u10 = *(const uint4*)(r10 + ks * 32);
            uint4 u11 = *(const uint4*)(r11 + ks * 32);
            uint4 ov;
            ov.x = bil2(u00.x, u01.x, u10.x, u11.x, w00, w01, w10, w11);
            ov.y = bil2(u00.y, u01.y, u10.y, u11.y, w00, w01, w10, w11);
            ov.z = bil2(u00.z, u01.z, u10.z, u11.z, w00, w01, w10, w11);
            ov.w = bil2(u00.w, u01.w, u10.w, u11.w, w00, w01, w10, w11);
            afrag[ks] = __builtin_bit_cast(v8s, ov);
        }

        const unsigned short* wk = wb2 + (size_t)(k * 64 + m) * 64 + g * 8;
#pragma unroll
        for (int nt = 0; nt < 4; ++nt) {
#pragma unroll
            for (int ks = 0; ks < 2; ++ks) {
                v8s bb = *(const v8s*)(wk + nt * 16 * 64 + ks * 32);
                acc[nt] = __builtin_amdgcn_mfma_f32_16x16x32_bf16(
                    afrag[ks], bb, acc[nt], 0, 0, 0);
            }
        }
    }

    // D: row = g*4+reg (position), col = m; o = nt*16 + m
    float* op = out + ((size_t)(b * COUT + m)) * HW + hw0 + g * 4;
#pragma unroll
    for (int nt = 0; nt < 4; ++nt)
        *(v4f*)(op + (size_t)nt * 16 * HW) = acc[nt];
}

extern "C" void kernel_launch(void* const* d_in, const int* in_sizes, int n_in,
                              void* d_out, int out_size, void* d_ws, size_t ws_size,
                              hipStream_t stream)
{
    const float* frame_i = (const float*)d_in[0];
    const float* frame_j = (const float*)d_in[1];
    const float* flow_ij = (const float*)d_in[2];
    const float* w_off   = (const float*)d_in[3];
    const float* b_off   = (const float*)d_in[4];
    const float* w_mod   = (const float*)d_in[5];
    const float* b_mod   = (const float*)d_in[6];
    const float* w_reg   = (const float*)d_in[7];
    float* out = (float*)d_out;

    // workspace: Xt bf16 [NROW+1][160] | Wa2 | Wb2 (~12 MB)
    unsigned short* xt  = (unsigned short*)d_ws;
    unsigned short* wa2 = xt + (size_t)(NROW + 1) * C2B;
    unsigned short* wb2 = wa2 + NA;

    prep_kernel<<<XBLK + WBLK, 256, 0, stream>>>(
        frame_i, frame_j, flow_ij, w_off, w_mod, w_reg, xt, wa2, wb2);

    fused_kernel<<<NBLK, 256, 0, stream>>>(
        xt, wa2, wb2, b_off, b_mod, out);
}

// Round 8
// 140.393 us; speedup vs baseline: 1.0959x; 1.0959x over previous
//
#include <hip/hip_runtime.h>
#include <math.h>

#define BB   4
#define HH   96
#define WW   96
#define HW   (HH * WW)          // 9216
#define CIN  64
#define COUT 64
#define C2B  160                // bf16 concat channels padded 130 -> 160
#define NROW (BB * HW)          // 36864
#define ZROW NROW               // all-zero row for invalid conv taps
#define NSTRIP (NROW / 16)      // 2304 strips of 16 positions
#define SPX  (NSTRIP / 8)       // 288 strips per XCD
#define NA   (9 * 32 * C2B)     // wa2 elements (46080)
#define NW   (9 * 64 * 64)      // wb2 elements (36864)
#define PXBLK (NROW / 64)       // 576 transpose blocks (64 rows each)
#define PWBLK 324               // weight blocks covering NA+NW elements

typedef short v8s __attribute__((ext_vector_type(8)));   // 8 bf16 = 4 VGPRs
typedef float v4f __attribute__((ext_vector_type(4)));

__device__ __forceinline__ unsigned short f2bf(float f) {
    unsigned u = __float_as_uint(f);
    return (unsigned short)((u + 0x7FFFu + ((u >> 16) & 1u)) >> 16);  // RTN-even
}
__device__ __forceinline__ unsigned pack2(float a, float b) {
    return (unsigned)f2bf(a) | ((unsigned)f2bf(b) << 16);
}
// bilinear-combine one packed-bf16-pair dword from each of 4 corners
__device__ __forceinline__ unsigned bil2(unsigned a, unsigned b, unsigned c,
                                         unsigned d, float w00, float w01,
                                         float w10, float w11) {
    float lo = w00 * __uint_as_float(a << 16) + w01 * __uint_as_float(b << 16)
             + w10 * __uint_as_float(c << 16) + w11 * __uint_as_float(d << 16);
    float hi = w00 * __uint_as_float(a & 0xffff0000u)
             + w01 * __uint_as_float(b & 0xffff0000u)
             + w10 * __uint_as_float(c & 0xffff0000u)
             + w11 * __uint_as_float(d & 0xffff0000u);
    return pack2(lo, hi);
}

// ---------------------------------------------------------------------------
// Prep, single launch, three block ranges:
//  [0, PXBLK): tiled LDS transpose. Block handles 64 rows. Read coalesced
//    along hw (lane=position), pack bf16 pairs into LDS tile[64 pos][80 dw],
//    then write fully-coalesced dwordx4 (lane = dword-quad within row).
//  [PXBLK, PXBLK+PWBLK): weight transposes (tiny).
//  last block: zero row ZROW.
// Xt[row][160] bf16 = concat(fi[64], fj[64], flow[2], 0-pad).
// Wa2[t][oc(32)][ch(160)]; Wb2[k][o(64)][ch(64)] = w_reg[o][c][k].
// ---------------------------------------------------------------------------
__global__ __launch_bounds__(256) void prep_kernel(
    const float* __restrict__ fi, const float* __restrict__ fj,
    const float* __restrict__ fl, const float* __restrict__ w_off,
    const float* __restrict__ w_mod, const float* __restrict__ w_reg,
    unsigned short* __restrict__ xt, unsigned short* __restrict__ wa2,
    unsigned short* __restrict__ wb2)
{
    int blk = blockIdx.x;
    if (blk < PXBLK) {
        __shared__ __align__(16) unsigned tile[64 * 80];   // 20 KB
        int tid = threadIdx.x;
        int p = tid & 63, cg = tid >> 6;    // position, channel-group
        int r0 = blk * 64;
        int b = r0 / HW;                    // 64-row strip never straddles b
        int hw = r0 - b * HW + p;
        const float* pi = fi + (size_t)b * CIN * HW + hw;
        const float* pj = fj + (size_t)b * CIN * HW + hw;
#pragma unroll
        for (int d = 0; d < 8; ++d) {       // fi channels cg*16 .. cg*16+15
            int c = cg * 16 + 2 * d;
            tile[p * 80 + cg * 8 + d] =
                pack2(pi[(size_t)c * HW], pi[(size_t)(c + 1) * HW]);
        }
#pragma unroll
        for (int d = 0; d < 8; ++d) {       // fj channels
            int c = cg * 16 + 2 * d;
            tile[p * 80 + 32 + cg * 8 + d] =
                pack2(pj[(size_t)c * HW], pj[(size_t)(c + 1) * HW]);
        }
        if (cg == 0) {                      // flow + zero pad
            const float* pf = fl + (size_t)b * 2 * HW + hw;
            tile[p * 80 + 64] = pack2(pf[0], pf[HW]);
#pragma unroll
            for (int i = 65; i < 80; ++i) tile[p * 80 + i] = 0u;
        }
        __syncthreads();
        uint4* dst = (uint4*)(xt + (size_t)r0 * C2B);      // 20 quads per row
#pragma unroll
        for (int i = 0; i < 5; ++i) {       // 5*256 = 64 rows * 20 quads
            int gq = i * 256 + tid;
            int rl = gq / 20, c4 = gq - rl * 20;
            const unsigned* s = &tile[rl * 80 + c4 * 4];
            uint4 v = {s[0], s[1], s[2], s[3]};
            dst[gq] = v;
        }
    } else if (blk < PXBLK + PWBLK) {
        int e = (blk - PXBLK) * 256 + threadIdx.x;
        if (e < NA) {
            int c  = e % C2B;
            int oc = (e / C2B) % 32;
            int t  = e / (C2B * 32);
            float v = 0.0f;
            if (oc < 27 && c < 130) {
                if (oc < 18) v = w_off[((size_t)oc * 130 + c) * 9 + t];
                else         v = w_mod[((size_t)(oc - 18) * 130 + c) * 9 + t];
            }
            wa2[e] = f2bf(v);
        } else {
            int e2 = e - NA;
            if (e2 < NW) {
                int c = e2 % 64;
                int o = (e2 / 64) % 64;
                int k = e2 / 4096;
                wb2[e2] = f2bf(w_reg[((size_t)o * 64 + c) * 9 + k]);
            }
        }
    } else {
        if (threadIdx.x < 20) {             // zero row, 20 dwordx4
            uint4 z = {0u, 0u, 0u, 0u};
            ((uint4*)(xt + (size_t)ZROW * C2B))[threadIdx.x] = z;
        }
    }
}

// ---------------------------------------------------------------------------
// Conv (offset+modulator) as implicit-GEMM MFMA. 1 wave/block, 2304 blocks.
// M=16 positions x N=32 oc (two 16-tiles), K = 9 taps x 160. A straight from
// global Xt rows (border taps -> ZROW). Epilogue fuses bias / 2*sigmoid,
// stores raw[oc][pos] fp32 as dwordx4.
// ---------------------------------------------------------------------------
__global__ __launch_bounds__(64) void conv_mfma_kernel(
    const unsigned short* __restrict__ xt,
    const unsigned short* __restrict__ wa2,
    const float* __restrict__ b_off, const float* __restrict__ b_mod,
    float* __restrict__ raw)
{
    int l = threadIdx.x;
    int m = l & 15, g = l >> 4;
    int strip = (blockIdx.x & 7) * SPX + (blockIdx.x >> 3);   // XCD-contiguous
    int b = strip / (HW / 16);              // wave-uniform
    int hw0 = strip * 16 - b * HW;
    int hw = hw0 + m;
    int x = hw % WW, y = hw / WW;

    v4f acc0 = {0.f, 0.f, 0.f, 0.f};
    v4f acc1 = {0.f, 0.f, 0.f, 0.f};

#pragma unroll
    for (int t = 0; t < 9; ++t) {
        int ty = t / 3, tx = t - 3 * ty;
        int yy = y + ty - 1, xx = x + tx - 1;
        bool ok = ((unsigned)yy < HH) && ((unsigned)xx < WW);
        int row = ok ? (b * HW + yy * WW + xx) : ZROW;
        const unsigned short* ar = xt + (size_t)row * C2B + g * 8;
        const unsigned short* w0 = wa2 + ((size_t)(t * 32 + m)) * C2B + g * 8;
        const unsigned short* w1 = w0 + 16 * C2B;
#pragma unroll
        for (int ks = 0; ks < 5; ++ks) {
            v8s a  = *(const v8s*)(ar + ks * 32);
            v8s b0 = *(const v8s*)(w0 + ks * 32);
            v8s b1 = *(const v8s*)(w1 + ks * 32);
            acc0 = __builtin_amdgcn_mfma_f32_16x16x32_bf16(a, b0, acc0, 0, 0, 0);
            acc1 = __builtin_amdgcn_mfma_f32_16x16x32_bf16(a, b1, acc1, 0, 0, 0);
        }
    }

    // D: row = g*4+reg (position), col = m (oc within n-tile)
    int p0 = strip * 16 + g * 4;
    {   // n-tile 0: oc = m (all offset channels)
        float bo = b_off[m];
        v4f o0;
        o0.x = acc0.x + bo; o0.y = acc0.y + bo;
        o0.z = acc0.z + bo; o0.w = acc0.w + bo;
        *(v4f*)(raw + (size_t)m * NROW + p0) = o0;
    }
    int oc1 = 16 + m;
    if (oc1 < 27) {                          // 16,17 offset; 18..26 mod
        v4f o1;
        if (oc1 < 18) {
            float bo = b_off[oc1];
            o1.x = acc1.x + bo; o1.y = acc1.y + bo;
            o1.z = acc1.z + bo; o1.w = acc1.w + bo;
        } else {
            float bm = b_mod[oc1 - 18];
            o1.x = 2.0f / (1.0f + expf(-(acc1.x + bm)));
            o1.y = 2.0f / (1.0f + expf(-(acc1.y + bm)));
            o1.z = 2.0f / (1.0f + expf(-(acc1.z + bm)));
            o1.w = 2.0f / (1.0f + expf(-(acc1.w + bm)));
        }
        *(v4f*)(raw + (size_t)oc1 * NROW + p0) = o1;
    }
}

// ---------------------------------------------------------------------------
// Deformable conv, standalone. 1 wave/block, 2304 blocks, NO LDS/barriers.
// M=16 positions x N=64 outputs. All 27 offset/mod values prefetched, then
// per tap each lane (m,g) bilinear-gathers channels ks*32+g*8..+7 at the 4
// corners and combines DIRECTLY into the MFMA A-fragment; 8 MFMAs/tap.
// ---------------------------------------------------------------------------
__global__ __launch_bounds__(64) void deform_mfma_kernel(
    const unsigned short* __restrict__ xt,
    const unsigned short* __restrict__ wb2,
    const float* __restrict__ raw, float* __restrict__ out)
{
    int l = threadIdx.x;
    int m = l & 15, g = l >> 4;
    int strip = (blockIdx.x & 7) * SPX + (blockIdx.x >> 3);
    int b = strip / (HW / 16);
    int hw0 = strip * 16 - b * HW;
    int hw = hw0 + m;
    int x = hw % WW, y = hw / WW;
    int pidx = strip * 16 + m;

    // prefetch my position's 18 offsets + 9 modulators (independent loads)
    float offv[27];
#pragma unroll
    for (int i = 0; i < 27; ++i)
        offv[i] = raw[(size_t)i * NROW + pidx];

    v4f acc[4];
#pragma unroll
    for (int nt = 0; nt < 4; ++nt) acc[nt] = (v4f){0.f, 0.f, 0.f, 0.f};

#pragma unroll
    for (int k = 0; k < 9; ++k) {
        int ky = k / 3, kx = k - 3 * ky;
        float dy = offv[2 * k];
        float dx = offv[2 * k + 1];
        float mm = offv[18 + k];

        float py = (float)(y - 1 + ky) + dy;
        float px = (float)(x - 1 + kx) + dx;
        float fy = floorf(py), fx = floorf(px);
        int   y0 = (int)fy,    x0 = (int)fx;
        float wy = py - fy,    wx = px - fx;
        int   y1 = y0 + 1,     x1 = x0 + 1;

        bool y0v = (y0 >= 0) && (y0 < HH);
        bool y1v = (y1 >= 0) && (y1 < HH);
        bool x0v = (x0 >= 0) && (x0 < WW);
        bool x1v = (x1 >= 0) && (x1 < WW);

        float w00 = (1.f - wy) * (1.f - wx) * ((y0v && x0v) ? mm : 0.f);
        float w01 = (1.f - wy) * wx         * ((y0v && x1v) ? mm : 0.f);
        float w10 = wy * (1.f - wx)         * ((y1v && x0v) ? mm : 0.f);
        float w11 = wy * wx                 * ((y1v && x1v) ? mm : 0.f);

        int y0c = min(max(y0, 0), HH - 1), y1c = min(max(y1, 0), HH - 1);
        int x0c = min(max(x0, 0), WW - 1), x1c = min(max(x1, 0), WW - 1);
        int rb = b * HW;
        // fj channels at +64 in the row; lane's A-chunk = ks*32 + g*8
        const unsigned short* r00 = xt + (size_t)(rb + y0c * WW + x0c) * C2B + 64 + g * 8;
        const unsigned short* r01 = xt + (size_t)(rb + y0c * WW + x1c) * C2B + 64 + g * 8;
        const unsigned short* r10 = xt + (size_t)(rb + y1c * WW + x0c) * C2B + 64 + g * 8;
        const unsigned short* r11 = xt + (size_t)(rb + y1c * WW + x1c) * C2B + 64 + g * 8;

        v8s afrag[2];
#pragma unroll
        for (int ks = 0; ks < 2; ++ks) {
            uint4 u00 = *(const uint4*)(r00 + ks * 32);
            uint4 u01 = *(const uint4*)(r01 + ks * 32);
            uint4 u10 = *(const uint4*)(r10 + ks * 32);
            uint4 u11 = *(const uint4*)(r11 + ks * 32);
            uint4 ov;
            ov.x = bil2(u00.x, u01.x, u10.x, u11.x, w00, w01, w10, w11);
            ov.y = bil2(u00.y, u01.y, u10.y, u11.y, w00, w01, w10, w11);
            ov.z = bil2(u00.z, u01.z, u10.z, u11.z, w00, w01, w10, w11);
            ov.w = bil2(u00.w, u01.w, u10.w, u11.w, w00, w01, w10, w11);
            afrag[ks] = __builtin_bit_cast(v8s, ov);
        }

        const unsigned short* wk = wb2 + (size_t)(k * 64 + m) * 64 + g * 8;
#pragma unroll
        for (int nt = 0; nt < 4; ++nt) {
#pragma unroll
            for (int ks = 0; ks < 2; ++ks) {
                v8s bb = *(const v8s*)(wk + nt * 16 * 64 + ks * 32);
                acc[nt] = __builtin_amdgcn_mfma_f32_16x16x32_bf16(
                    afrag[ks], bb, acc[nt], 0, 0, 0);
            }
        }
    }

    // D: row = g*4+reg (position), col = m; o = nt*16 + m
    float* op = out + ((size_t)(b * COUT + m)) * HW + hw0 + g * 4;
#pragma unroll
    for (int nt = 0; nt < 4; ++nt)
        *(v4f*)(op + (size_t)nt * 16 * HW) = acc[nt];
}

extern "C" void kernel_launch(void* const* d_in, const int* in_sizes, int n_in,
                              void* d_out, int out_size, void* d_ws, size_t ws_size,
                              hipStream_t stream)
{
    const float* frame_i = (const float*)d_in[0];
    const float* frame_j = (const float*)d_in[1];
    const float* flow_ij = (const float*)d_in[2];
    const float* w_off   = (const float*)d_in[3];
    const float* b_off   = (const float*)d_in[4];
    const float* w_mod   = (const float*)d_in[5];
    const float* b_mod   = (const float*)d_in[6];
    const float* w_reg   = (const float*)d_in[7];
    float* out = (float*)d_out;

    // workspace: Xt bf16 [NROW+1][160] | Wa2 | Wb2 | raw fp32 [28][NROW]
    unsigned short* xt  = (unsigned short*)d_ws;
    unsigned short* wa2 = xt + (size_t)(NROW + 1) * C2B;
    unsigned short* wb2 = wa2 + NA;
    float*          raw = (float*)(wb2 + NW);

    prep_kernel<<<PXBLK + PWBLK + 1, 256, 0, stream>>>(
        frame_i, frame_j, flow_ij, w_off, w_mod, w_reg, xt, wa2, wb2);

    conv_mfma_kernel<<<NSTRIP, 64, 0, stream>>>(xt, wa2, b_off, b_mod, raw);
    deform_mfma_kernel<<<NSTRIP, 64, 0, stream>>>(xt, wb2, raw, out);
}

// Round 9
// 139.838 us; speedup vs baseline: 1.1003x; 1.0040x over previous
//
#include <hip/hip_runtime.h>
#include <math.h>

#define BB   4
#define HH   96
#define WW   96
#define HW   (HH * WW)          // 9216
#define CIN  64
#define COUT 64
#define C2B  160                // bf16 concat channels padded 130 -> 160
#define NROW (BB * HW)          // 36864
#define ZROW NROW               // all-zero row for invalid conv taps
#define NSTRIP (NROW / 16)      // 2304 strips of 16 positions
#define SPX  (NSTRIP / 8)       // 288 strips per XCD
#define NA   (9 * 32 * C2B)     // wa2 elements (46080)
#define NW   (9 * 64 * 64)      // wb2 elements (36864)
#define PXBLK (NROW / 64)       // 576 transpose blocks (64 rows each)
#define PWBLK 324               // weight blocks covering NA+NW elements
#define TS   81                 // LDS tile row stride in dwords (80 + 1 pad:
                                // stride 80 -> banks {0,16} only, 32-way
                                // conflict; 81 -> gcd(17,32)=1, conflict-free)

typedef short v8s __attribute__((ext_vector_type(8)));   // 8 bf16 = 4 VGPRs
typedef float v4f __attribute__((ext_vector_type(4)));

__device__ __forceinline__ unsigned short f2bf(float f) {
    unsigned u = __float_as_uint(f);
    return (unsigned short)((u + 0x7FFFu + ((u >> 16) & 1u)) >> 16);  // RTN-even
}
__device__ __forceinline__ unsigned pack2(float a, float b) {
    return (unsigned)f2bf(a) | ((unsigned)f2bf(b) << 16);
}
// bilinear-combine one packed-bf16-pair dword from each of 4 corners
__device__ __forceinline__ unsigned bil2(unsigned a, unsigned b, unsigned c,
                                         unsigned d, float w00, float w01,
                                         float w10, float w11) {
    float lo = w00 * __uint_as_float(a << 16) + w01 * __uint_as_float(b << 16)
             + w10 * __uint_as_float(c << 16) + w11 * __uint_as_float(d << 16);
    float hi = w00 * __uint_as_float(a & 0xffff0000u)
             + w01 * __uint_as_float(b & 0xffff0000u)
             + w10 * __uint_as_float(c & 0xffff0000u)
             + w11 * __uint_as_float(d & 0xffff0000u);
    return pack2(lo, hi);
}

// ---------------------------------------------------------------------------
// Prep, single launch, three block ranges:
//  [0, PXBLK): tiled LDS transpose, 64 rows/block. Coalesced channel-plane
//    reads -> LDS tile[64][TS] (padded stride, conflict-free) -> coalesced
//    dwordx4 row writes.
//  [PXBLK, PXBLK+PWBLK): weight transposes (tiny).
//  last block: zero row ZROW.
// Xt[row][160] bf16 = concat(fi[64], fj[64], flow[2], 0-pad).
// Wa2[t][oc(32)][ch(160)]; Wb2[k][o(64)][ch(64)] = w_reg[o][c][k].
// ---------------------------------------------------------------------------
__global__ __launch_bounds__(256) void prep_kernel(
    const float* __restrict__ fi, const float* __restrict__ fj,
    const float* __restrict__ fl, const float* __restrict__ w_off,
    const float* __restrict__ w_mod, const float* __restrict__ w_reg,
    unsigned short* __restrict__ xt, unsigned short* __restrict__ wa2,
    unsigned short* __restrict__ wb2)
{
    int blk = blockIdx.x;
    if (blk < PXBLK) {
        __shared__ __align__(16) unsigned tile[64 * TS];   // 20.7 KB
        int tid = threadIdx.x;
        int p = tid & 63, cg = tid >> 6;    // position, channel-group
        int r0 = blk * 64;
        int b = r0 / HW;                    // 64-row strip never straddles b
        int hw = r0 - b * HW + p;
        const float* pi = fi + (size_t)b * CIN * HW + hw;
        const float* pj = fj + (size_t)b * CIN * HW + hw;
#pragma unroll
        for (int d = 0; d < 8; ++d) {       // fi channels cg*16 .. cg*16+15
            int c = cg * 16 + 2 * d;
            tile[p * TS + cg * 8 + d] =
                pack2(pi[(size_t)c * HW], pi[(size_t)(c + 1) * HW]);
        }
#pragma unroll
        for (int d = 0; d < 8; ++d) {       // fj channels
            int c = cg * 16 + 2 * d;
            tile[p * TS + 32 + cg * 8 + d] =
                pack2(pj[(size_t)c * HW], pj[(size_t)(c + 1) * HW]);
        }
        if (cg == 0) {                      // flow + zero pad
            const float* pf = fl + (size_t)b * 2 * HW + hw;
            tile[p * TS + 64] = pack2(pf[0], pf[HW]);
#pragma unroll
            for (int i = 65; i < 80; ++i) tile[p * TS + i] = 0u;
        }
        __syncthreads();
        uint4* dst = (uint4*)(xt + (size_t)r0 * C2B);      // 20 quads per row
#pragma unroll
        for (int i = 0; i < 5; ++i) {       // 5*256 = 64 rows * 20 quads
            int gq = i * 256 + tid;
            int rl = gq / 20, c4 = gq - rl * 20;
            const unsigned* s = &tile[rl * TS + c4 * 4];
            uint4 v = {s[0], s[1], s[2], s[3]};
            dst[gq] = v;
        }
    } else if (blk < PXBLK + PWBLK) {
        int e = (blk - PXBLK) * 256 + threadIdx.x;
        if (e < NA) {
            int c  = e % C2B;
            int oc = (e / C2B) % 32;
            int t  = e / (C2B * 32);
            float v = 0.0f;
            if (oc < 27 && c < 130) {
                if (oc < 18) v = w_off[((size_t)oc * 130 + c) * 9 + t];
                else         v = w_mod[((size_t)(oc - 18) * 130 + c) * 9 + t];
            }
            wa2[e] = f2bf(v);
        } else {
            int e2 = e - NA;
            if (e2 < NW) {
                int c = e2 % 64;
                int o = (e2 / 64) % 64;
                int k = e2 / 4096;
                wb2[e2] = f2bf(w_reg[((size_t)o * 64 + c) * 9 + k]);
            }
        }
    } else {
        if (threadIdx.x < 20) {             // zero row, 20 dwordx4
            uint4 z = {0u, 0u, 0u, 0u};
            ((uint4*)(xt + (size_t)ZROW * C2B))[threadIdx.x] = z;
        }
    }
}

// ---------------------------------------------------------------------------
// Conv (offset+modulator) as implicit-GEMM MFMA. 1 wave/block, 2304 blocks.
// M=16 positions x N=32 oc (two 16-tiles), K = 9 taps x 160. A straight from
// global Xt rows (border taps -> ZROW). Epilogue fuses bias / 2*sigmoid,
// stores raw[oc][pos] fp32 as dwordx4.
// ---------------------------------------------------------------------------
__global__ __launch_bounds__(64) void conv_mfma_kernel(
    const unsigned short* __restrict__ xt,
    const unsigned short* __restrict__ wa2,
    const float* __restrict__ b_off, const float* __restrict__ b_mod,
    float* __restrict__ raw)
{
    int l = threadIdx.x;
    int m = l & 15, g = l >> 4;
    int strip = (blockIdx.x & 7) * SPX + (blockIdx.x >> 3);   // XCD-contiguous
    int b = strip / (HW / 16);              // wave-uniform
    int hw0 = strip * 16 - b * HW;
    int hw = hw0 + m;
    int x = hw % WW, y = hw / WW;

    v4f acc0 = {0.f, 0.f, 0.f, 0.f};
    v4f acc1 = {0.f, 0.f, 0.f, 0.f};

#pragma unroll
    for (int t = 0; t < 9; ++t) {
        int ty = t / 3, tx = t - 3 * ty;
        int yy = y + ty - 1, xx = x + tx - 1;
        bool ok = ((unsigned)yy < HH) && ((unsigned)xx < WW);
        int row = ok ? (b * HW + yy * WW + xx) : ZROW;
        const unsigned short* ar = xt + (size_t)row * C2B + g * 8;
        const unsigned short* w0 = wa2 + ((size_t)(t * 32 + m)) * C2B + g * 8;
        const unsigned short* w1 = w0 + 16 * C2B;
#pragma unroll
        for (int ks = 0; ks < 5; ++ks) {
            v8s a  = *(const v8s*)(ar + ks * 32);
            v8s b0 = *(const v8s*)(w0 + ks * 32);
            v8s b1 = *(const v8s*)(w1 + ks * 32);
            acc0 = __builtin_amdgcn_mfma_f32_16x16x32_bf16(a, b0, acc0, 0, 0, 0);
            acc1 = __builtin_amdgcn_mfma_f32_16x16x32_bf16(a, b1, acc1, 0, 0, 0);
        }
    }

    // D: row = g*4+reg (position), col = m (oc within n-tile)
    int p0 = strip * 16 + g * 4;
    {   // n-tile 0: oc = m (all offset channels)
        float bo = b_off[m];
        v4f o0;
        o0.x = acc0.x + bo; o0.y = acc0.y + bo;
        o0.z = acc0.z + bo; o0.w = acc0.w + bo;
        *(v4f*)(raw + (size_t)m * NROW + p0) = o0;
    }
    int oc1 = 16 + m;
    if (oc1 < 27) {                          // 16,17 offset; 18..26 mod
        v4f o1;
        if (oc1 < 18) {
            float bo = b_off[oc1];
            o1.x = acc1.x + bo; o1.y = acc1.y + bo;
            o1.z = acc1.z + bo; o1.w = acc1.w + bo;
        } else {
            float bm = b_mod[oc1 - 18];
            o1.x = 2.0f / (1.0f + expf(-(acc1.x + bm)));
            o1.y = 2.0f / (1.0f + expf(-(acc1.y + bm)));
            o1.z = 2.0f / (1.0f + expf(-(acc1.z + bm)));
            o1.w = 2.0f / (1.0f + expf(-(acc1.w + bm)));
        }
        *(v4f*)(raw + (size_t)oc1 * NROW + p0) = o1;
    }
}

// ---------------------------------------------------------------------------
// Deformable conv, standalone. 1 wave/block, 2304 blocks, NO LDS/barriers.
// M=16 positions x N=64 outputs. All 27 offset/mod values prefetched, then
// per tap each lane (m,g) bilinear-gathers channels ks*32+g*8..+7 at the 4
// corners and combines DIRECTLY into the MFMA A-fragment; 8 MFMAs/tap.
// ---------------------------------------------------------------------------
__global__ __launch_bounds__(64) void deform_mfma_kernel(
    const unsigned short* __restrict__ xt,
    const unsigned short* __restrict__ wb2,
    const float* __restrict__ raw, float* __restrict__ out)
{
    int l = threadIdx.x;
    int m = l & 15, g = l >> 4;
    int strip = (blockIdx.x & 7) * SPX + (blockIdx.x >> 3);
    int b = strip / (HW / 16);
    int hw0 = strip * 16 - b * HW;
    int hw = hw0 + m;
    int x = hw % WW, y = hw / WW;
    int pidx = strip * 16 + m;

    // prefetch my position's 18 offsets + 9 modulators (independent loads)
    float offv[27];
#pragma unroll
    for (int i = 0; i < 27; ++i)
        offv[i] = raw[(size_t)i * NROW + pidx];

    v4f acc[4];
#pragma unroll
    for (int nt = 0; nt < 4; ++nt) acc[nt] = (v4f){0.f, 0.f, 0.f, 0.f};

#pragma unroll
    for (int k = 0; k < 9; ++k) {
        int ky = k / 3, kx = k - 3 * ky;
        float dy = offv[2 * k];
        float dx = offv[2 * k + 1];
        float mm = offv[18 + k];

        float py = (float)(y - 1 + ky) + dy;
        float px = (float)(x - 1 + kx) + dx;
        float fy = floorf(py), fx = floorf(px);
        int   y0 = (int)fy,    x0 = (int)fx;
        float wy = py - fy,    wx = px - fx;
        int   y1 = y0 + 1,     x1 = x0 + 1;

        bool y0v = (y0 >= 0) && (y0 < HH);
        bool y1v = (y1 >= 0) && (y1 < HH);
        bool x0v = (x0 >= 0) && (x0 < WW);
        bool x1v = (x1 >= 0) && (x1 < WW);

        float w00 = (1.f - wy) * (1.f - wx) * ((y0v && x0v) ? mm : 0.f);
        float w01 = (1.f - wy) * wx         * ((y0v && x1v) ? mm : 0.f);
        float w10 = wy * (1.f - wx)         * ((y1v && x0v) ? mm : 0.f);
        float w11 = wy * wx                 * ((y1v && x1v) ? mm : 0.f);

        int y0c = min(max(y0, 0), HH - 1), y1c = min(max(y1, 0), HH - 1);
        int x0c = min(max(x0, 0), WW - 1), x1c = min(max(x1, 0), WW - 1);
        int rb = b * HW;
        // fj channels at +64 in the row; lane's A-chunk = ks*32 + g*8
        const unsigned short* r00 = xt + (size_t)(rb + y0c * WW + x0c) * C2B + 64 + g * 8;
        const unsigned short* r01 = xt + (size_t)(rb + y0c * WW + x1c) * C2B + 64 + g * 8;
        const unsigned short* r10 = xt + (size_t)(rb + y1c * WW + x0c) * C2B + 64 + g * 8;
        const unsigned short* r11 = xt + (size_t)(rb + y1c * WW + x1c) * C2B + 64 + g * 8;

        v8s afrag[2];
#pragma unroll
        for (int ks = 0; ks < 2; ++ks) {
            uint4 u00 = *(const uint4*)(r00 + ks * 32);
            uint4 u01 = *(const uint4*)(r01 + ks * 32);
            uint4 u10 = *(const uint4*)(r10 + ks * 32);
            uint4 u11 = *(const uint4*)(r11 + ks * 32);
            uint4 ov;
            ov.x = bil2(u00.x, u01.x, u10.x, u11.x, w00, w01, w10, w11);
            ov.y = bil2(u00.y, u01.y, u10.y, u11.y, w00, w01, w10, w11);
            ov.z = bil2(u00.z, u01.z, u10.z, u11.z, w00, w01, w10, w11);
            ov.w = bil2(u00.w, u01.w, u10.w, u11.w, w00, w01, w10, w11);
            afrag[ks] = __builtin_bit_cast(v8s, ov);
        }

        const unsigned short* wk = wb2 + (size_t)(k * 64 + m) * 64 + g * 8;
#pragma unroll
        for (int nt = 0; nt < 4; ++nt) {
#pragma unroll
            for (int ks = 0; ks < 2; ++ks) {
                v8s bb = *(const v8s*)(wk + nt * 16 * 64 + ks * 32);
                acc[nt] = __builtin_amdgcn_mfma_f32_16x16x32_bf16(
                    afrag[ks], bb, acc[nt], 0, 0, 0);
            }
        }
    }

    // D: row = g*4+reg (position), col = m; o = nt*16 + m
    float* op = out + ((size_t)(b * COUT + m)) * HW + hw0 + g * 4;
#pragma unroll
    for (int nt = 0; nt < 4; ++nt)
        *(v4f*)(op + (size_t)nt * 16 * HW) = acc[nt];
}

extern "C" void kernel_launch(void* const* d_in, const int* in_sizes, int n_in,
                              void* d_out, int out_size, void* d_ws, size_t ws_size,
                              hipStream_t stream)
{
    const float* frame_i = (const float*)d_in[0];
    const float* frame_j = (const float*)d_in[1];
    const float* flow_ij = (const float*)d_in[2];
    const float* w_off   = (const float*)d_in[3];
    const float* b_off   = (const float*)d_in[4];
    const float* w_mod   = (const float*)d_in[5];
    const float* b_mod   = (const float*)d_in[6];
    const float* w_reg   = (const float*)d_in[7];
    float* out = (float*)d_out;

    // workspace: Xt bf16 [NROW+1][160] | Wa2 | Wb2 | raw fp32 [28][NROW]
    unsigned short* xt  = (unsigned short*)d_ws;
    unsigned short* wa2 = xt + (size_t)(NROW + 1) * C2B;
    unsigned short* wb2 = wa2 + NA;
    float*          raw = (float*)(wb2 + NW);

    prep_kernel<<<PXBLK + PWBLK + 1, 256, 0, stream>>>(
        frame_i, frame_j, flow_ij, w_off, w_mod, w_reg, xt, wa2, wb2);

    conv_mfma_kernel<<<NSTRIP, 64, 0, stream>>>(xt, wa2, b_off, b_mod, raw);
    deform_mfma_kernel<<<NSTRIP, 64, 0, stream>>>(xt, wb2, raw, out);
}